// Round 2
// baseline (1356.276 us; speedup 1.0000x reference)
//
#include <hip/hip_runtime.h>
#include <hip/hip_bf16.h>

#define BLK   256
#define NSAMP 558
#define NRAYS 2048
#define RESI  160
#define R2I   25600
#define R3I   4096000
#define NTOT  (NRAYS * NSAMP)          // 1,142,784
#define SAMP_BLOCKS (NTOT / BLK)       // 4464 exact
#define RAYSTRIDE 32
#define NVOX  4096000                  // 160^3
#define TG_BLOCKS (NVOX / BLK)         // 16000 exact

#define ACT_SHIFT_F (-4.5951198501345896f)
#define STEP_F 0.00625f   // STEPSIZE * VOXEL

// ---------------- ws layout ----------------
// [0]          int flag
// [256]        float rayData[2048*32]            (262,144 B)
// [262400]     float4 samp[2048*558]             (18,284,544 B)
// [18546944]   ushort tgrid[160^3 * 16]          (131,072,000 B)   [big path only]
// [149618944]  float4 lat[3 * NTOT]              (54,853,632 B)    [split path only]
#define RAYDATA_OFF 256
#define SAMP_OFF    (RAYDATA_OFF + NRAYS * RAYSTRIDE * 4)
#define TG_OFF      (SAMP_OFF + (size_t)NTOT * 16)
#define WS_BIG      (TG_OFF + (size_t)NVOX * 32)
#define LAT_OFF     WS_BIG
#define WS_SPLIT    (LAT_OFF + (size_t)NTOT * 48)

template <typename T> __device__ __forceinline__ float ldv(const T* p, int i);
template <> __device__ __forceinline__ float ldv<float>(const float* p, int i) { return p[i]; }
template <> __device__ __forceinline__ float ldv<__hip_bfloat16>(const __hip_bfloat16* p, int i) {
    return __bfloat162float(p[i]);
}
template <typename T> __device__ __forceinline__ T cvt_out(float v);
template <> __device__ __forceinline__ float cvt_out<float>(float v) { return v; }
template <> __device__ __forceinline__ __hip_bfloat16 cvt_out<__hip_bfloat16>(float v) {
    return __float2bfloat16(v);
}
__device__ __forceinline__ float b2f(unsigned short u) {
    union { float f; unsigned int i; } c; c.i = ((unsigned int)u) << 16; return c.f;
}
__device__ __forceinline__ float blo(unsigned int u) {
    union { float f; unsigned int i; } c; c.i = u << 16; return c.f;
}
__device__ __forceinline__ float bhi(unsigned int u) {
    union { float f; unsigned int i; } c; c.i = u & 0xffff0000u; return c.f;
}
__device__ __forceinline__ unsigned short f2b(float v) {
    __hip_bfloat16 h = __float2bfloat16(v);
    unsigned short u;
    __builtin_memcpy(&u, &h, sizeof(u));
    return u;
}

template <typename T>
struct KParams {
    const T *rays_o, *rays_d, *viewdirs, *grid;
    const T *aw1,*ab1,*aw2,*ab2,*aw3,*ab3;
    const T *pw1,*pb1,*pw2,*pb2,*pw3,*pb3;
    const T *dw1,*db1,*dw2,*db2,*dw3,*db3,*dw4,*db4;
    T *out;
    const int* flag;
    float* rayData;
    float4* samp;
    unsigned short* tgrid;
    float4* lat;     // [3*NTOT]: A=lat[idx], B=lat[NTOT+idx], C=lat[2*NTOT+idx]
    int want;
};

// ---- dtype detector: viewdirs rows are unit-norm under the TRUE dtype ----
__global__ void detect_dtype(const void* vd, int* flag) {
    if (threadIdx.x == 0 && blockIdx.x == 0) {
        const float* f = (const float*)vd;
        const __hip_bfloat16* h = (const __hip_bfloat16*)vd;
        float sf = 0.f, sb = 0.f;
        for (int r = 0; r < 8; ++r) {
            float a = f[r*3], b = f[r*3+1], c = f[r*3+2];
            float d = (a*a + b*b + c*c) - 1.f;
            sf += d*d;
            float a2 = __bfloat162float(h[r*3]);
            float b2 = __bfloat162float(h[r*3+1]);
            float c2 = __bfloat162float(h[r*3+2]);
            float d2 = (a2*a2 + b2*b2 + c2*c2) - 1.f;
            sb += d2*d2;
        }
        bool sf_ok = (sf == sf) && (sf < 1e30f);
        bool sb_ok = (sb == sb) && (sb < 1e30f);
        int fl = 0;
        if (sb_ok && (!sf_ok || sb < sf)) fl = 1;
        *flag = fl;
    }
}

// =============== Transpose: (12, X, Y, Z) -> voxel-major [X][Y][Z][16ch] bf16 ===============
template <typename T>
__global__ __launch_bounds__(BLK)
void transpose_k(KParams<T> P) {
    if (*P.flag != P.want) return;
    const int i = blockIdx.x * BLK + threadIdx.x;
    unsigned short r[16];
    #pragma unroll
    for (int c = 0; c < 12; ++c) r[c] = f2b(ldv<T>(P.grid, c * R3I + i));
    #pragma unroll
    for (int c = 12; c < 16; ++c) r[c] = 0;
    uint4* dst = (uint4*)(P.tgrid + (size_t)i * 16);
    uint4 w0, w1;
    w0.x = (unsigned int)r[0] | ((unsigned int)r[1] << 16);
    w0.y = (unsigned int)r[2] | ((unsigned int)r[3] << 16);
    w0.z = (unsigned int)r[4] | ((unsigned int)r[5] << 16);
    w0.w = (unsigned int)r[6] | ((unsigned int)r[7] << 16);
    w1.x = (unsigned int)r[8] | ((unsigned int)r[9] << 16);
    w1.y = (unsigned int)r[10] | ((unsigned int)r[11] << 16);
    w1.z = 0; w1.w = 0;
    dst[0] = w0; dst[1] = w1;
}

// =============== Kernel 1: per-ray prep ===============
template <typename T>
__global__ __launch_bounds__(BLK)
void prep_k(KParams<T> P) {
    if (*P.flag != P.want) return;
    __shared__ float semb[BLK * 39];
    const int tid = threadIdx.x;
    const int ray = blockIdx.x * BLK + tid;
    if (ray >= NRAYS) return;
    const float ox = ldv<T>(P.rays_o, ray*3+0);
    const float oy = ldv<T>(P.rays_o, ray*3+1);
    const float oz = ldv<T>(P.rays_o, ray*3+2);
    const float dx = ldv<T>(P.rays_d, ray*3+0);
    const float dy = ldv<T>(P.rays_d, ray*3+1);
    const float dz = ldv<T>(P.rays_d, ray*3+2);
    const float vx = (dx == 0.f) ? 1e-6f : dx;
    const float vy = (dy == 0.f) ? 1e-6f : dy;
    const float vz = (dz == 0.f) ? 1e-6f : dz;
    const float rax = (1.f - ox) / vx, rbx = (-1.f - ox) / vx;
    const float ray_ = (1.f - oy) / vy, rby = (-1.f - oy) / vy;
    const float raz = (1.f - oz) / vz, rbz = (-1.f - oz) / vz;
    float tmin = fmaxf(fmaxf(fminf(rax, rbx), fminf(ray_, rby)), fminf(raz, rbz));
    float tmax = fminf(fminf(fmaxf(rax, rbx), fmaxf(ray_, rby)), fmaxf(raz, rbz));
    tmin = fminf(fmaxf(tmin, 0.05f), 3.5f);
    tmax = fminf(fmaxf(tmax, 0.05f), 3.5f);
    const bool mask_ray = (tmax <= tmin);
    const float norm_d = sqrtf(dx*dx + dy*dy + dz*dz);
    const float inv_nd = 1.f / norm_d;
    {
        float v0 = ldv<T>(P.viewdirs, ray*3+0);
        float v1 = ldv<T>(P.viewdirs, ray*3+1);
        float v2 = ldv<T>(P.viewdirs, ray*3+2);
        float* e = semb + tid*39;
        e[0] = v0; e[1] = v1; e[2] = v2;
        #pragma unroll
        for (int l = 0; l < 6; ++l) {
            float f = (float)(1 << l);
            e[3 + l*6 + 0] = __sinf(v0*f);
            e[3 + l*6 + 1] = __sinf(v1*f);
            e[3 + l*6 + 2] = __sinf(v2*f);
            e[3 + l*6 + 3] = __cosf(v0*f);
            e[3 + l*6 + 4] = __cosf(v1*f);
            e[3 + l*6 + 5] = __cosf(v2*f);
        }
    }
    float acc[16];
    #pragma unroll
    for (int j = 0; j < 16; ++j) acc[j] = ldv<T>(P.db1, j);
    const float* e = semb + tid*39;
    for (int i = 0; i < 39; ++i) {
        float xi = e[i];
        #pragma unroll
        for (int j = 0; j < 16; ++j) acc[j] = fmaf(xi, ldv<T>(P.dw1, (15+i)*16 + j), acc[j]);
    }
    float* rd = P.rayData + ray * RAYSTRIDE;
    rd[0] = ox; rd[1] = oy; rd[2] = oz;
    rd[3] = dx; rd[4] = dy; rd[5] = dz;
    rd[6] = mask_ray ? __int_as_float(0x7fc00000) : tmin;
    rd[7] = inv_nd;
    #pragma unroll
    for (int j = 0; j < 16; ++j) rd[8 + j] = acc[j];
    rd[24] = tmin * norm_d;
}

// =============== shared LDS weight layout for sample kernels ===============
#define AW1_O 0
#define AB1_O 480
#define AW2_O 512
#define AB2_O 1536
#define AW3_O 1568
#define AB3_O 1696
#define PW1_O 1700
#define PB1_O 1892
#define PW2_O 1908
#define PB2_O 2164
#define PW3_O 2180
#define PB3_O 2436
#define DW1_O 2452   /* rows 0..14 only: 240 */
#define DW2_O 2692
#define DB2_O 2948
#define DW3_O 2964
#define DB3_O 3220
#define DW4_O 3236   /* PADDED: 16 rows x 4 floats (col 3 = 0) */
#define DB4_O 3300   /* PADDED: 4 floats (last = 0) */
#define SW2_FLOATS 3304

template <typename T>
__device__ __forceinline__ void stage_w(float* dst, const T* src, int n, int tid) {
    for (int i = tid; i < n; i += BLK) dst[i] = ldv<T>(src, i);
}

template <typename T>
__device__ __forceinline__ void stage_all(float* sw, const KParams<T>& P, int tid) {
    stage_w(sw + AW1_O, P.aw1, 480, tid);
    stage_w(sw + AB1_O, P.ab1, 32, tid);
    stage_w(sw + AW2_O, P.aw2, 1024, tid);
    stage_w(sw + AB2_O, P.ab2, 32, tid);
    stage_w(sw + AW3_O, P.aw3, 128, tid);
    stage_w(sw + AB3_O, P.ab3, 4, tid);
    stage_w(sw + PW1_O, P.pw1, 192, tid);
    stage_w(sw + PB1_O, P.pb1, 16, tid);
    stage_w(sw + PW2_O, P.pw2, 256, tid);
    stage_w(sw + PB2_O, P.pb2, 16, tid);
    stage_w(sw + PW3_O, P.pw3, 256, tid);
    stage_w(sw + PB3_O, P.pb3, 16, tid);
    stage_w(sw + DW1_O, P.dw1, 240, tid);
    stage_w(sw + DW2_O, P.dw2, 256, tid);
    stage_w(sw + DB2_O, P.db2, 16, tid);
    stage_w(sw + DW3_O, P.dw3, 256, tid);
    stage_w(sw + DB3_O, P.db3, 16, tid);
    // dw4 padded to 16x4 (col 3 zero) so every weight access is a 16B vector load
    for (int i = tid; i < 64; i += BLK) {
        int r = i >> 2, c = i & 3;
        sw[DW4_O + i] = (c < 3) ? ldv<T>(P.dw4, r*3 + c) : 0.f;
    }
    if (tid < 4) sw[DB4_O + tid] = (tid < 3) ? ldv<T>(P.db4, tid) : 0.f;
}

// ---- register-resident float4 helpers (no local arrays anywhere -> scratch impossible) ----
__device__ __forceinline__ float4 lds4(const float* p) { return *(const float4*)p; }
__device__ __forceinline__ void fma4(float4& a, float s, float4 w) {
    a.x = fmaf(s, w.x, a.x); a.y = fmaf(s, w.y, a.y);
    a.z = fmaf(s, w.z, a.z); a.w = fmaf(s, w.w, a.w);
}
__device__ __forceinline__ void relu4(float4& a) {
    a.x = fmaxf(a.x, 0.f); a.y = fmaxf(a.y, 0.f);
    a.z = fmaxf(a.z, 0.f); a.w = fmaxf(a.w, 0.f);
}

// Full MLP chain, fully macro-expanded with literal indices.
// lat = (A,B,C) float4s; returns float4(alpha, r, g, b).
__device__ __forceinline__ float4 mlp_macro(const float* sw, const float* rd,
                                            float4 A, float4 B, float4 C,
                                            float px, float py, float pz) {
    // ---- attention layer 1: in[15] = {pz,py,px, lat0..11} -> 32 ----
    float4 q0 = lds4(sw+AB1_O+0),  q1 = lds4(sw+AB1_O+4),
           q2 = lds4(sw+AB1_O+8),  q3 = lds4(sw+AB1_O+12),
           q4 = lds4(sw+AB1_O+16), q5 = lds4(sw+AB1_O+20),
           q6 = lds4(sw+AB1_O+24), q7 = lds4(sw+AB1_O+28);
#define L1ROW(i, s_) { const float* W_ = sw + AW1_O + (i)*32; const float s = (s_); \
    fma4(q0,s,lds4(W_+0));  fma4(q1,s,lds4(W_+4));  fma4(q2,s,lds4(W_+8));  fma4(q3,s,lds4(W_+12)); \
    fma4(q4,s,lds4(W_+16)); fma4(q5,s,lds4(W_+20)); fma4(q6,s,lds4(W_+24)); fma4(q7,s,lds4(W_+28)); }
    L1ROW(0,pz) L1ROW(1,py) L1ROW(2,px)
    L1ROW(3,A.x) L1ROW(4,A.y) L1ROW(5,A.z) L1ROW(6,A.w)
    L1ROW(7,B.x) L1ROW(8,B.y) L1ROW(9,B.z) L1ROW(10,B.w)
    L1ROW(11,C.x) L1ROW(12,C.y) L1ROW(13,C.z) L1ROW(14,C.w)
#undef L1ROW
    relu4(q0); relu4(q1); relu4(q2); relu4(q3);
    relu4(q4); relu4(q5); relu4(q6); relu4(q7);

    // ---- attention layers 2+3, blocked by output group c (8 cols at a time) ----
    float4 lg = lds4(sw+AB3_O);
#define A2ROW(c,i,s_) { const float* W_ = sw + AW2_O + (i)*32 + (c)*8; const float s = (s_); \
    fma4(t0,s,lds4(W_)); fma4(t1,s,lds4(W_+4)); }
#define A2Q(c,i0,qv) A2ROW(c,(i0)+0,qv.x) A2ROW(c,(i0)+1,qv.y) A2ROW(c,(i0)+2,qv.z) A2ROW(c,(i0)+3,qv.w)
#define A3F(c,j,t_) { const float s = fmaxf((t_),0.f); fma4(lg,s,lds4(sw + AW3_O + ((c)*8+(j))*4)); }
#define ABLK(c) { float4 t0 = lds4(sw+AB2_O+(c)*8); float4 t1 = lds4(sw+AB2_O+(c)*8+4); \
    A2Q(c,0,q0) A2Q(c,4,q1) A2Q(c,8,q2) A2Q(c,12,q3) \
    A2Q(c,16,q4) A2Q(c,20,q5) A2Q(c,24,q6) A2Q(c,28,q7) \
    A3F(c,0,t0.x) A3F(c,1,t0.y) A3F(c,2,t0.z) A3F(c,3,t0.w) \
    A3F(c,4,t1.x) A3F(c,5,t1.y) A3F(c,6,t1.z) A3F(c,7,t1.w) }
    ABLK(0) ABLK(1) ABLK(2) ABLK(3)
#undef ABLK
#undef A3F
#undef A2Q
#undef A2ROW
    float m = fmaxf(fmaxf(lg.x,lg.y), fmaxf(lg.z,lg.w));
    float e0 = __expf(lg.x-m), e1 = __expf(lg.y-m), e2 = __expf(lg.z-m), e3 = __expf(lg.w-m);
    float att1 = e1 / (e0+e1+e2+e3);

#define R16(i, s_, BASE, r0,r1,r2,r3) { const float* W_ = sw + (BASE) + (i)*16; const float s = (s_); \
    fma4(r0,s,lds4(W_)); fma4(r1,s,lds4(W_+4)); fma4(r2,s,lds4(W_+8)); fma4(r3,s,lds4(W_+12)); }
#define R16Q(i0, qv, BASE, r0,r1,r2,r3) \
    R16((i0)+0,qv.x,BASE,r0,r1,r2,r3) R16((i0)+1,qv.y,BASE,r0,r1,r2,r3) \
    R16((i0)+2,qv.z,BASE,r0,r1,r2,r3) R16((i0)+3,qv.w,BASE,r0,r1,r2,r3)

    // ---- pos net: lat -> 16 -> 16 -> 16 ----
    float4 u0 = lds4(sw+PB1_O), u1 = lds4(sw+PB1_O+4), u2 = lds4(sw+PB1_O+8), u3 = lds4(sw+PB1_O+12);
    R16Q(0,A,PW1_O,u0,u1,u2,u3) R16Q(4,B,PW1_O,u0,u1,u2,u3) R16Q(8,C,PW1_O,u0,u1,u2,u3)
    relu4(u0); relu4(u1); relu4(u2); relu4(u3);
    float4 v0 = lds4(sw+PB2_O), v1 = lds4(sw+PB2_O+4), v2 = lds4(sw+PB2_O+8), v3 = lds4(sw+PB2_O+12);
    R16Q(0,u0,PW2_O,v0,v1,v2,v3) R16Q(4,u1,PW2_O,v0,v1,v2,v3)
    R16Q(8,u2,PW2_O,v0,v1,v2,v3) R16Q(12,u3,PW2_O,v0,v1,v2,v3)
    relu4(v0); relu4(v1); relu4(v2); relu4(v3);
    float4 o0 = lds4(sw+PB3_O), o1 = lds4(sw+PB3_O+4), o2 = lds4(sw+PB3_O+8), o3 = lds4(sw+PB3_O+12);
    R16Q(0,v0,PW3_O,o0,o1,o2,o3) R16Q(4,v1,PW3_O,o0,o1,o2,o3)
    R16Q(8,v2,PW3_O,o0,o1,o2,o3) R16Q(12,v3,PW3_O,o0,o1,o2,o3)

    // ---- decoder: d1 = relu(dw1 @ po[1..15] + precomputed emb part from rd[8..23]) ----
    const float4* rdv = (const float4*)(rd + 8);
    float4 d0 = rdv[0], d1 = rdv[1], d2 = rdv[2], d3 = rdv[3];
    R16(0,o0.y,DW1_O,d0,d1,d2,d3) R16(1,o0.z,DW1_O,d0,d1,d2,d3) R16(2,o0.w,DW1_O,d0,d1,d2,d3)
    R16Q(3,o1,DW1_O,d0,d1,d2,d3) R16Q(7,o2,DW1_O,d0,d1,d2,d3) R16Q(11,o3,DW1_O,d0,d1,d2,d3)
    relu4(d0); relu4(d1); relu4(d2); relu4(d3);
    float4 g0 = lds4(sw+DB2_O), g1 = lds4(sw+DB2_O+4), g2 = lds4(sw+DB2_O+8), g3 = lds4(sw+DB2_O+12);
    R16Q(0,d0,DW2_O,g0,g1,g2,g3) R16Q(4,d1,DW2_O,g0,g1,g2,g3)
    R16Q(8,d2,DW2_O,g0,g1,g2,g3) R16Q(12,d3,DW2_O,g0,g1,g2,g3)
    relu4(g0); relu4(g1); relu4(g2); relu4(g3);
    float4 h0 = lds4(sw+DB3_O), h1 = lds4(sw+DB3_O+4), h2 = lds4(sw+DB3_O+8), h3 = lds4(sw+DB3_O+12);
    R16Q(0,g0,DW3_O,h0,h1,h2,h3) R16Q(4,g1,DW3_O,h0,h1,h2,h3)
    R16Q(8,g2,DW3_O,h0,h1,h2,h3) R16Q(12,g3,DW3_O,h0,h1,h2,h3)
    relu4(h0); relu4(h1); relu4(h2); relu4(h3);
    float4 rr = lds4(sw+DB4_O);
#define R4(i, s_) { fma4(rr,(s_),lds4(sw + DW4_O + (i)*4)); }
    R4(0,h0.x) R4(1,h0.y) R4(2,h0.z) R4(3,h0.w)
    R4(4,h1.x) R4(5,h1.y) R4(6,h1.z) R4(7,h1.w)
    R4(8,h2.x) R4(9,h2.y) R4(10,h2.z) R4(11,h2.w)
    R4(12,h3.x) R4(13,h3.y) R4(14,h3.z) R4(15,h3.w)
#undef R4
#undef R16Q
#undef R16
    float dens = att1 * o0.x;
    float xsh = dens + ACT_SHIFT_F;
    float sp = (xsh > 0.f) ? xsh + log1pf(__expf(-xsh)) : log1pf(__expf(xsh));
    float4 res;
    res.x = 1.f - __expf(-sp * 0.5f);
    res.y = 1.f / (1.f + __expf(-att1 * rr.x));
    res.z = 1.f / (1.f + __expf(-att1 * rr.y));
    res.w = 1.f / (1.f + __expf(-att1 * rr.z));
    return res;
}

// =============== SPLIT PATH kernel A: pure trilinear gather -> lat buffer ===============
template <typename T>
__global__ __launch_bounds__(BLK, 4)
void gather_tg_k(KParams<T> P) {
    if (*P.flag != P.want) return;
    const int idx = blockIdx.x * BLK + threadIdx.x;
    const int ray = idx / NSAMP;
    const int s   = idx - ray * NSAMP;
    const float* rd = P.rayData + ray * RAYSTRIDE;
    const float tmin = rd[6], inv_nd = rd[7];
    const float it = fmaf(STEP_F * (float)s, inv_nd, tmin);
    const float px = fmaf(rd[3], it, rd[0]);
    const float py = fmaf(rd[4], it, rd[1]);
    const float pz = fmaf(rd[5], it, rd[2]);
    bool inb = (px >= -1.f) & (px <= 1.f) & (py >= -1.f) & (py <= 1.f)
             & (pz >= -1.f) & (pz <= 1.f);
    if (!inb) return;   // mlp_split_k recomputes inb identically; lat never read for OOB
    float gx = (px + 1.f) * 79.5f;
    float gy = (py + 1.f) * 79.5f;
    float gz = (pz + 1.f) * 79.5f;
    float fx0 = floorf(gx), fy0 = floorf(gy), fz0 = floorf(gz);
    float frx = gx - fx0, fry = gy - fy0, frz = gz - fz0;
    int x0 = min(max((int)fx0, 0), RESI-1); int x1 = min(x0+1, RESI-1);
    int y0 = min(max((int)fy0, 0), RESI-1); int y1 = min(y0+1, RESI-1);
    int z0 = min(max((int)fz0, 0), RESI-1); int z1 = min(z0+1, RESI-1);
    int bx0 = x0*R2I, bx1 = x1*R2I, by0 = y0*RESI, by1 = y1*RESI;
    float wx0 = 1.f-frx, wy0 = 1.f-fry, wz0 = 1.f-frz;
    float4 LA = make_float4(0.f,0.f,0.f,0.f);
    float4 LB = make_float4(0.f,0.f,0.f,0.f);
    float4 LC = make_float4(0.f,0.f,0.f,0.f);
#define CORNER(OFF, W_) { const unsigned short* vp = P.tgrid + (OFF)*16; \
    uint4 a_ = *(const uint4*)vp; uint2 b_ = *(const uint2*)(vp + 8); const float w = (W_); \
    LA.x = fmaf(w, blo(a_.x), LA.x); LA.y = fmaf(w, bhi(a_.x), LA.y); \
    LA.z = fmaf(w, blo(a_.y), LA.z); LA.w = fmaf(w, bhi(a_.y), LA.w); \
    LB.x = fmaf(w, blo(a_.z), LB.x); LB.y = fmaf(w, bhi(a_.z), LB.y); \
    LB.z = fmaf(w, blo(a_.w), LB.z); LB.w = fmaf(w, bhi(a_.w), LB.w); \
    LC.x = fmaf(w, blo(b_.x), LC.x); LC.y = fmaf(w, bhi(b_.x), LC.y); \
    LC.z = fmaf(w, blo(b_.y), LC.z); LC.w = fmaf(w, bhi(b_.y), LC.w); }
    CORNER(bx0+by0+z0, wx0*wy0*wz0)
    CORNER(bx0+by0+z1, wx0*wy0*frz)
    CORNER(bx0+by1+z0, wx0*fry*wz0)
    CORNER(bx0+by1+z1, wx0*fry*frz)
    CORNER(bx1+by0+z0, frx*wy0*wz0)
    CORNER(bx1+by0+z1, frx*wy0*frz)
    CORNER(bx1+by1+z0, frx*fry*wz0)
    CORNER(bx1+by1+z1, frx*fry*frz)
#undef CORNER
    P.lat[idx]          = LA;
    P.lat[NTOT + idx]   = LB;
    P.lat[2*NTOT + idx] = LC;
}

// =============== SPLIT PATH kernel B: streaming MLP over precomputed latents ===============
template <typename T>
__global__ __launch_bounds__(BLK, 3)
void mlp_split_k(KParams<T> P) {
    if (*P.flag != P.want) return;
    __shared__ float sw[SW2_FLOATS];
    const int tid = threadIdx.x;
    stage_all(sw, P, tid);
    __syncthreads();

    const int idx = blockIdx.x * BLK + tid;
    const int ray = idx / NSAMP;
    const int s   = idx - ray * NSAMP;
    const float* rd = P.rayData + ray * RAYSTRIDE;
    const float tmin = rd[6], inv_nd = rd[7];
    const float it = fmaf(STEP_F * (float)s, inv_nd, tmin);
    const float px = fmaf(rd[3], it, rd[0]);
    const float py = fmaf(rd[4], it, rd[1]);
    const float pz = fmaf(rd[5], it, rd[2]);
    bool inb = (px >= -1.f) & (px <= 1.f) & (py >= -1.f) & (py <= 1.f)
             & (pz >= -1.f) & (pz <= 1.f);
    float4 res = make_float4(0.f, 0.f, 0.f, 0.f);
    if (inb) {
        float4 A = P.lat[idx];
        float4 B = P.lat[NTOT + idx];
        float4 C = P.lat[2*NTOT + idx];
        res = mlp_macro(sw, rd, A, B, C, px, py, pz);
    }
    P.samp[idx] = res;
}

// =============== Kernel 2 (big path): fused gather + MLP, AoS transposed grid ===============
template <typename T>
__global__ __launch_bounds__(BLK, 3)
void sample_tg_k(KParams<T> P) {
    if (*P.flag != P.want) return;
    __shared__ float sw[SW2_FLOATS];
    const int tid = threadIdx.x;
    stage_all(sw, P, tid);
    __syncthreads();

    const int idx = blockIdx.x * BLK + tid;
    const int ray = idx / NSAMP;
    const int s   = idx - ray * NSAMP;
    const float* rd = P.rayData + ray * RAYSTRIDE;
    const float tmin = rd[6], inv_nd = rd[7];
    const float it = fmaf(STEP_F * (float)s, inv_nd, tmin);
    const float px = fmaf(rd[3], it, rd[0]);
    const float py = fmaf(rd[4], it, rd[1]);
    const float pz = fmaf(rd[5], it, rd[2]);
    bool inb = (px >= -1.f) & (px <= 1.f) & (py >= -1.f) & (py <= 1.f)
             & (pz >= -1.f) & (pz <= 1.f);
    float4 res = make_float4(0.f, 0.f, 0.f, 0.f);
    if (inb) {
        float gx = (px + 1.f) * 79.5f;
        float gy = (py + 1.f) * 79.5f;
        float gz = (pz + 1.f) * 79.5f;
        float fx0 = floorf(gx), fy0 = floorf(gy), fz0 = floorf(gz);
        float frx = gx - fx0, fry = gy - fy0, frz = gz - fz0;
        int x0 = min(max((int)fx0, 0), RESI-1); int x1 = min(x0+1, RESI-1);
        int y0 = min(max((int)fy0, 0), RESI-1); int y1 = min(y0+1, RESI-1);
        int z0 = min(max((int)fz0, 0), RESI-1); int z1 = min(z0+1, RESI-1);
        int bx0 = x0*R2I, bx1 = x1*R2I, by0 = y0*RESI, by1 = y1*RESI;
        float wx0 = 1.f-frx, wy0 = 1.f-fry, wz0 = 1.f-frz;
        float4 LA = make_float4(0.f,0.f,0.f,0.f);
        float4 LB = make_float4(0.f,0.f,0.f,0.f);
        float4 LC = make_float4(0.f,0.f,0.f,0.f);
#define CORNER(OFF, W_) { const unsigned short* vp = P.tgrid + (OFF)*16; \
        uint4 a_ = *(const uint4*)vp; uint2 b_ = *(const uint2*)(vp + 8); const float w = (W_); \
        LA.x = fmaf(w, blo(a_.x), LA.x); LA.y = fmaf(w, bhi(a_.x), LA.y); \
        LA.z = fmaf(w, blo(a_.y), LA.z); LA.w = fmaf(w, bhi(a_.y), LA.w); \
        LB.x = fmaf(w, blo(a_.z), LB.x); LB.y = fmaf(w, bhi(a_.z), LB.y); \
        LB.z = fmaf(w, blo(a_.w), LB.z); LB.w = fmaf(w, bhi(a_.w), LB.w); \
        LC.x = fmaf(w, blo(b_.x), LC.x); LC.y = fmaf(w, bhi(b_.x), LC.y); \
        LC.z = fmaf(w, blo(b_.y), LC.z); LC.w = fmaf(w, bhi(b_.y), LC.w); }
        CORNER(bx0+by0+z0, wx0*wy0*wz0)
        CORNER(bx0+by0+z1, wx0*wy0*frz)
        CORNER(bx0+by1+z0, wx0*fry*wz0)
        CORNER(bx0+by1+z1, wx0*fry*frz)
        CORNER(bx1+by0+z0, frx*wy0*wz0)
        CORNER(bx1+by0+z1, frx*wy0*frz)
        CORNER(bx1+by1+z0, frx*fry*wz0)
        CORNER(bx1+by1+z1, frx*fry*frz)
#undef CORNER
        res = mlp_macro(sw, rd, LA, LB, LC, px, py, pz);
    }
    P.samp[idx] = res;
}

// =============== Kernel 2 (mid fallback): scattered gather from original grid ===============
template <typename T>
__global__ __launch_bounds__(BLK, 3)
void sample_k(KParams<T> P) {
    if (*P.flag != P.want) return;
    __shared__ float sw[SW2_FLOATS];
    const int tid = threadIdx.x;
    stage_all(sw, P, tid);
    __syncthreads();

    const int idx = blockIdx.x * BLK + tid;
    const int ray = idx / NSAMP;
    const int s   = idx - ray * NSAMP;
    const float* rd = P.rayData + ray * RAYSTRIDE;
    const float tmin = rd[6], inv_nd = rd[7];
    const float it = fmaf(STEP_F * (float)s, inv_nd, tmin);
    const float px = fmaf(rd[3], it, rd[0]);
    const float py = fmaf(rd[4], it, rd[1]);
    const float pz = fmaf(rd[5], it, rd[2]);
    bool inb = (px >= -1.f) & (px <= 1.f) & (py >= -1.f) & (py <= 1.f)
             & (pz >= -1.f) & (pz <= 1.f);
    float4 res = make_float4(0.f, 0.f, 0.f, 0.f);
    if (inb) {
        float gx = (px + 1.f) * 79.5f;
        float gy = (py + 1.f) * 79.5f;
        float gz = (pz + 1.f) * 79.5f;
        float fx0 = floorf(gx), fy0 = floorf(gy), fz0 = floorf(gz);
        float frx = gx - fx0, fry = gy - fy0, frz = gz - fz0;
        int x0 = min(max((int)fx0, 0), RESI-1); int x1 = min(x0+1, RESI-1);
        int y0 = min(max((int)fy0, 0), RESI-1); int y1 = min(y0+1, RESI-1);
        int z0 = min(max((int)fz0, 0), RESI-1); int z1 = min(z0+1, RESI-1);
        int bx0 = x0*R2I, bx1 = x1*R2I, by0 = y0*RESI, by1 = y1*RESI;
        int o000 = bx0+by0+z0, o001 = bx0+by0+z1, o010 = bx0+by1+z0, o011 = bx0+by1+z1;
        int o100 = bx1+by0+z0, o101 = bx1+by0+z1, o110 = bx1+by1+z0, o111 = bx1+by1+z1;
        float wx0 = 1.f-frx, wy0 = 1.f-fry, wz0 = 1.f-frz;
        float w000 = wx0*wy0*wz0, w001 = wx0*wy0*frz, w010 = wx0*fry*wz0, w011 = wx0*fry*frz;
        float w100 = frx*wy0*wz0, w101 = frx*wy0*frz, w110 = frx*fry*wz0, w111 = frx*fry*frz;
        float lat[12];
        #pragma unroll
        for (int c = 0; c < 12; ++c) {
            const T* g = P.grid + c*R3I;
            lat[c] = w000*ldv<T>(g,o000) + w001*ldv<T>(g,o001)
                   + w010*ldv<T>(g,o010) + w011*ldv<T>(g,o011)
                   + w100*ldv<T>(g,o100) + w101*ldv<T>(g,o101)
                   + w110*ldv<T>(g,o110) + w111*ldv<T>(g,o111);
        }
        float4 LA = make_float4(lat[0], lat[1], lat[2],  lat[3]);
        float4 LB = make_float4(lat[4], lat[5], lat[6],  lat[7]);
        float4 LC = make_float4(lat[8], lat[9], lat[10], lat[11]);
        res = mlp_macro(sw, rd, LA, LB, LC, px, py, pz);
    }
    P.samp[idx] = res;
}

// =============== Kernel 3: per-ray composite (one wave per ray) ===============
template <typename T>
__global__ __launch_bounds__(64)
void composite_k(KParams<T> P) {
    if (*P.flag != P.want) return;
    const int ray = blockIdx.x;
    const int lane = threadIdx.x;
    const float base_depth = P.rayData[ray * RAYSTRIDE + 24];
    const float4* sp = P.samp + ray * NSAMP;
    float lp = 1.f, cr = 0.f, cg = 0.f, cb = 0.f, cd = 0.f, ca = 0.f;
    #pragma unroll
    for (int k = 0; k < 9; ++k) {
        int s = lane * 9 + k;
        if (s < NSAMP) {
            float4 sm = sp[s];
            float w = sm.x * lp;
            cr += w * sm.y;
            cg += w * sm.z;
            cb += w * sm.w;
            cd += w * (base_depth + STEP_F * (float)s);
            ca += w;
            lp *= fmaxf(1.f - sm.x, 1e-10f);
        }
    }
    float pincl = lp;
    #pragma unroll
    for (int off = 1; off < 64; off <<= 1) {
        float v = __shfl_up(pincl, off, 64);
        if (lane >= off) pincl *= v;
    }
    float Tf = __shfl(pincl, 63, 64);
    float excl = __shfl_up(pincl, 1, 64);
    if (lane == 0) excl = 1.f;
    cr *= excl; cg *= excl; cb *= excl; cd *= excl; ca *= excl;
    #pragma unroll
    for (int off = 32; off > 0; off >>= 1) {
        cr += __shfl_down(cr, off, 64);
        cg += __shfl_down(cg, off, 64);
        cb += __shfl_down(cb, off, 64);
        cd += __shfl_down(cd, off, 64);
        ca += __shfl_down(ca, off, 64);
    }
    if (lane == 0) {
        float depth_m = cd + Tf * 3.5f;
        T* o = P.out + ray*6;
        o[0] = cvt_out<T>(cr + Tf);
        o[1] = cvt_out<T>(cg + Tf);
        o[2] = cvt_out<T>(cb + Tf);
        o[3] = cvt_out<T>(depth_m);
        o[4] = cvt_out<T>(1.f / depth_m);
        o[5] = cvt_out<T>(ca);
    }
}

template <typename T>
static void fill_params(KParams<T>& P, void* const* d_in, void* d_out, void* d_ws, int want) {
    P.rays_o   = (const T*)d_in[0];
    P.rays_d   = (const T*)d_in[1];
    P.viewdirs = (const T*)d_in[2];
    P.grid     = (const T*)d_in[3];
    P.aw1 = (const T*)d_in[4];  P.ab1 = (const T*)d_in[5];
    P.aw2 = (const T*)d_in[6];  P.ab2 = (const T*)d_in[7];
    P.aw3 = (const T*)d_in[8];  P.ab3 = (const T*)d_in[9];
    P.pw1 = (const T*)d_in[10]; P.pb1 = (const T*)d_in[11];
    P.pw2 = (const T*)d_in[12]; P.pb2 = (const T*)d_in[13];
    P.pw3 = (const T*)d_in[14]; P.pb3 = (const T*)d_in[15];
    P.dw1 = (const T*)d_in[16]; P.db1 = (const T*)d_in[17];
    P.dw2 = (const T*)d_in[18]; P.db2 = (const T*)d_in[19];
    P.dw3 = (const T*)d_in[20]; P.db3 = (const T*)d_in[21];
    P.dw4 = (const T*)d_in[22]; P.db4 = (const T*)d_in[23];
    P.out = (T*)d_out;
    P.flag = (const int*)d_ws;
    P.rayData = (float*)((char*)d_ws + RAYDATA_OFF);
    P.samp = (float4*)((char*)d_ws + SAMP_OFF);
    P.tgrid = (unsigned short*)((char*)d_ws + TG_OFF);
    P.lat = (float4*)((char*)d_ws + LAT_OFF);
    P.want = want;
}

extern "C" void kernel_launch(void* const* d_in, const int* in_sizes, int n_in,
                              void* d_out, int out_size, void* d_ws, size_t ws_size,
                              hipStream_t stream) {
    int* flag = (int*)d_ws;
    hipLaunchKernelGGL(detect_dtype, dim3(1), dim3(64), 0, stream, d_in[2], flag);

    KParams<float> Pf;
    fill_params<float>(Pf, d_in, d_out, d_ws, 0);
    KParams<__hip_bfloat16> Pb;
    fill_params<__hip_bfloat16>(Pb, d_in, d_out, d_ws, 1);

    hipLaunchKernelGGL(prep_k<float>, dim3((NRAYS + BLK - 1)/BLK), dim3(BLK), 0, stream, Pf);
    hipLaunchKernelGGL(prep_k<__hip_bfloat16>, dim3((NRAYS + BLK - 1)/BLK), dim3(BLK), 0, stream, Pb);

    if (ws_size >= WS_SPLIT) {
        hipLaunchKernelGGL(transpose_k<float>, dim3(TG_BLOCKS), dim3(BLK), 0, stream, Pf);
        hipLaunchKernelGGL(transpose_k<__hip_bfloat16>, dim3(TG_BLOCKS), dim3(BLK), 0, stream, Pb);
        hipLaunchKernelGGL(gather_tg_k<float>, dim3(SAMP_BLOCKS), dim3(BLK), 0, stream, Pf);
        hipLaunchKernelGGL(gather_tg_k<__hip_bfloat16>, dim3(SAMP_BLOCKS), dim3(BLK), 0, stream, Pb);
        hipLaunchKernelGGL(mlp_split_k<float>, dim3(SAMP_BLOCKS), dim3(BLK), 0, stream, Pf);
        hipLaunchKernelGGL(mlp_split_k<__hip_bfloat16>, dim3(SAMP_BLOCKS), dim3(BLK), 0, stream, Pb);
    } else if (ws_size >= WS_BIG) {
        hipLaunchKernelGGL(transpose_k<float>, dim3(TG_BLOCKS), dim3(BLK), 0, stream, Pf);
        hipLaunchKernelGGL(transpose_k<__hip_bfloat16>, dim3(TG_BLOCKS), dim3(BLK), 0, stream, Pb);
        hipLaunchKernelGGL(sample_tg_k<float>, dim3(SAMP_BLOCKS), dim3(BLK), 0, stream, Pf);
        hipLaunchKernelGGL(sample_tg_k<__hip_bfloat16>, dim3(SAMP_BLOCKS), dim3(BLK), 0, stream, Pb);
    } else {
        hipLaunchKernelGGL(sample_k<float>, dim3(SAMP_BLOCKS), dim3(BLK), 0, stream, Pf);
        hipLaunchKernelGGL(sample_k<__hip_bfloat16>, dim3(SAMP_BLOCKS), dim3(BLK), 0, stream, Pb);
    }
    hipLaunchKernelGGL(composite_k<float>, dim3(NRAYS), dim3(64), 0, stream, Pf);
    hipLaunchKernelGGL(composite_k<__hip_bfloat16>, dim3(NRAYS), dim3(64), 0, stream, Pb);
}